// Round 1
// baseline (2783.073 us; speedup 1.0000x reference)
//
#include <hip/hip_runtime.h>
#include <hip/hip_bf16.h>
#include <math.h>

#define DIN 512
#define DIM 512
#define NHEADS 8
#define DHEAD 64
#define NB 32

typedef __attribute__((ext_vector_type(8))) short bf16x8;
typedef __attribute__((ext_vector_type(4))) float f32x4;

__device__ inline unsigned short f2bf(float x) {
  unsigned int u = __float_as_uint(x);
  unsigned int r = (u + 0x7FFFu + ((u >> 16) & 1u)) >> 16;
  return (unsigned short)r;
}
__device__ inline float bf2f(unsigned short h) {
  return __uint_as_float(((unsigned int)h) << 16);
}

// ---------------- LayerNorm: one wave (64 lanes) per row of 512 ----------------
__global__ __launch_bounds__(256) void ln_kernel(const float* __restrict__ z,
                                                 const float* __restrict__ gamma,
                                                 const float* __restrict__ beta,
                                                 unsigned short* __restrict__ zn,
                                                 int ntot) {
  int wave = (blockIdx.x * blockDim.x + threadIdx.x) >> 6;
  int lane = threadIdx.x & 63;
  if (wave >= ntot) return;
  const float* row = z + (size_t)wave * DIN;
  float4 a = ((const float4*)row)[lane];
  float4 b = ((const float4*)row)[64 + lane];
  float s  = a.x + a.y + a.z + a.w + b.x + b.y + b.z + b.w;
  float sq = a.x*a.x + a.y*a.y + a.z*a.z + a.w*a.w
           + b.x*b.x + b.y*b.y + b.z*b.z + b.w*b.w;
#pragma unroll
  for (int off = 32; off; off >>= 1) {
    s  += __shfl_xor(s, off);
    sq += __shfl_xor(sq, off);
  }
  float mu  = s * (1.0f / DIN);
  float var = sq * (1.0f / DIN) - mu * mu;
  float r   = rsqrtf(var + 1e-5f);

  float4 g0 = ((const float4*)gamma)[lane];
  float4 g1 = ((const float4*)gamma)[64 + lane];
  float4 b0 = ((const float4*)beta)[lane];
  float4 b1 = ((const float4*)beta)[64 + lane];

  ushort4 o0, o1;
  o0.x = f2bf((a.x - mu) * r * g0.x + b0.x);
  o0.y = f2bf((a.y - mu) * r * g0.y + b0.y);
  o0.z = f2bf((a.z - mu) * r * g0.z + b0.z);
  o0.w = f2bf((a.w - mu) * r * g0.w + b0.w);
  o1.x = f2bf((b.x - mu) * r * g1.x + b1.x);
  o1.y = f2bf((b.y - mu) * r * g1.y + b1.y);
  o1.z = f2bf((b.z - mu) * r * g1.z + b1.z);
  o1.w = f2bf((b.w - mu) * r * g1.w + b1.w);
  ((ushort4*)(zn + (size_t)wave * DIN))[lane] = o0;
  ((ushort4*)(zn + (size_t)wave * DIN))[64 + lane] = o1;
}

// ---------------- graph starts via binary search over sorted src ----------------
__global__ void starts_kernel(const int* __restrict__ src, int* __restrict__ starts, int ntot) {
  int b = threadIdx.x;
  if (b > NB) return;
  int lo = 0, hi = ntot;
  while (lo < hi) {
    int mid = (lo + hi) >> 1;
    if (src[mid] < b) lo = mid + 1; else hi = mid;
  }
  starts[b] = lo;
}

// ---------------- weight transpose + bf16 convert: Wt[n][k] = W[k][n] ----------------
__global__ __launch_bounds__(256) void wtrans_kernel(const float* __restrict__ W,
                                                     unsigned short* __restrict__ Wt) {
  __shared__ float tile[32][33];
  int k0 = blockIdx.x * 32;
  int n0 = blockIdx.y * 32;
  int tx = threadIdx.x & 31;
  int ty = threadIdx.x >> 5;  // 0..7
#pragma unroll
  for (int i = 0; i < 4; i++)
    tile[ty + i * 8][tx] = W[(size_t)(k0 + ty + i * 8) * DIM + n0 + tx];
  __syncthreads();
#pragma unroll
  for (int i = 0; i < 4; i++)
    Wt[(size_t)(n0 + ty + i * 8) * DIN + k0 + tx] = f2bf(tile[tx][ty + i * 8]);
}

// ---------------- bf16 MFMA GEMM, B^T layout: C[m][n] = sum_k A[m][k]*Bt[n][k] ----------------
// wave computes 16(M) x 64(N); block = 4 waves = 64(M) x 64(N)
template <int N, bool BIAS, bool OUT_F32>
__global__ __launch_bounds__(256) void gemm_bt(const unsigned short* __restrict__ A,
                                               const unsigned short* __restrict__ Bt,
                                               const float* __restrict__ bias,
                                               unsigned short* __restrict__ Cbf,
                                               float* __restrict__ Cf) {
  int lane = threadIdx.x & 63;
  int wv   = threadIdx.x >> 6;
  int m0   = (blockIdx.x * 4 + wv) * 16;
  int n0   = blockIdx.y * 64;
  int quad = lane >> 4;
  int mi   = lane & 15;

  const unsigned short* arow = A  + (size_t)(m0 + mi) * DIN + quad * 8;
  const unsigned short* brow = Bt + (size_t)(n0 + mi) * DIN + quad * 8;

  f32x4 acc0 = {0.f, 0.f, 0.f, 0.f};
  f32x4 acc1 = {0.f, 0.f, 0.f, 0.f};
  f32x4 acc2 = {0.f, 0.f, 0.f, 0.f};
  f32x4 acc3 = {0.f, 0.f, 0.f, 0.f};

#pragma unroll 4
  for (int k = 0; k < DIN; k += 32) {
    bf16x8 af  = *(const bf16x8*)(arow + k);
    bf16x8 bf0 = *(const bf16x8*)(brow + k);
    bf16x8 bf1 = *(const bf16x8*)(brow + 16 * DIN + k);
    bf16x8 bf2 = *(const bf16x8*)(brow + 32 * DIN + k);
    bf16x8 bf3 = *(const bf16x8*)(brow + 48 * DIN + k);
    acc0 = __builtin_amdgcn_mfma_f32_16x16x32_bf16(af, bf0, acc0, 0, 0, 0);
    acc1 = __builtin_amdgcn_mfma_f32_16x16x32_bf16(af, bf1, acc1, 0, 0, 0);
    acc2 = __builtin_amdgcn_mfma_f32_16x16x32_bf16(af, bf2, acc2, 0, 0, 0);
    acc3 = __builtin_amdgcn_mfma_f32_16x16x32_bf16(af, bf3, acc3, 0, 0, 0);
  }

  f32x4 accs[4] = {acc0, acc1, acc2, acc3};
  int r0 = m0 + quad * 4;
#pragma unroll
  for (int j = 0; j < 4; j++) {
    int col = n0 + j * 16 + mi;
    float bv = BIAS ? bias[col] : 0.f;
#pragma unroll
    for (int r = 0; r < 4; r++) {
      float val = accs[j][r] + bv;
      size_t idx = (size_t)(r0 + r) * N + col;
      if (OUT_F32) Cf[idx] = val; else Cbf[idx] = f2bf(val);
    }
  }
}

// ---------------- attention: one wave per (row, head); lane = d; online softmax ----------------
__global__ __launch_bounds__(256) void attn_kernel(const unsigned short* __restrict__ qkv,
                                                   const int* __restrict__ starts,
                                                   const int* __restrict__ src,
                                                   unsigned short* __restrict__ o,
                                                   int ntot) {
  int id   = (int)((blockIdx.x * (unsigned)blockDim.x + threadIdx.x) >> 6);
  int lane = threadIdx.x & 63;
  int h    = id / ntot;
  int row  = id - h * ntot;
  int g    = src[row];
  int st   = starts[g];
  int en   = starts[g + 1];

  float qd = bf2f(qkv[(size_t)row * 1536 + h * 64 + lane]) * 0.125f;  // 1/sqrt(64)
  const unsigned short* kbase = qkv + 512 + h * 64 + lane;            // + node*1536
  float m = -INFINITY, l = 0.f, acc = 0.f;

  for (int node = st; node < en; node++) {
    float kd = bf2f(kbase[(size_t)node * 1536]);
    float t = qd * kd;
#pragma unroll
    for (int off = 32; off; off >>= 1) t += __shfl_xor(t, off);
    float mn = fmaxf(m, t);
    float c = __expf(m - mn);
    float p = __expf(t - mn);
    float vd = bf2f(kbase[(size_t)node * 1536 + 512]);
    l = l * c + p;
    acc = acc * c + p * vd;
    m = mn;
  }
  o[(size_t)row * DIM + h * 64 + lane] = f2bf(acc / l);
}

extern "C" void kernel_launch(void* const* d_in, const int* in_sizes, int n_in,
                              void* d_out, int out_size, void* d_ws, size_t ws_size,
                              hipStream_t stream) {
  const float* z     = (const float*)d_in[0];
  const int*   src   = (const int*)d_in[1];
  const float* gamma = (const float*)d_in[2];
  const float* beta  = (const float*)d_in[3];
  const float* Wq    = (const float*)d_in[4];
  const float* Wk    = (const float*)d_in[5];
  const float* Wv    = (const float*)d_in[6];
  const float* Wo    = (const float*)d_in[7];
  const float* bo    = (const float*)d_in[8];
  int ntot = in_sizes[0] / DIN;
  float* out = (float*)d_out;

  char* ws = (char*)d_ws;
  size_t off = 0;
  unsigned short* zn    = (unsigned short*)(ws + off); off += (size_t)ntot * DIN * 2;
  unsigned short* qkv   = (unsigned short*)(ws + off); off += (size_t)ntot * 1536 * 2;
  unsigned short* obuf  = (unsigned short*)(ws + off); off += (size_t)ntot * DIM * 2;
  unsigned short* WtQKV = (unsigned short*)(ws + off); off += (size_t)1536 * DIN * 2;
  unsigned short* WtO   = (unsigned short*)(ws + off); off += (size_t)DIM * DIN * 2;
  int* starts           = (int*)(ws + off);

  // weight prep: WtQKV rows [0,512)=Wq cols, [512,1024)=Wk, [1024,1536)=Wv; WtO=Wo^T
  wtrans_kernel<<<dim3(16, 16), 256, 0, stream>>>(Wq, WtQKV);
  wtrans_kernel<<<dim3(16, 16), 256, 0, stream>>>(Wk, WtQKV + (size_t)512 * DIN);
  wtrans_kernel<<<dim3(16, 16), 256, 0, stream>>>(Wv, WtQKV + (size_t)1024 * DIN);
  wtrans_kernel<<<dim3(16, 16), 256, 0, stream>>>(Wo, WtO);

  ln_kernel<<<ntot / 4, 256, 0, stream>>>(z, gamma, beta, zn, ntot);
  starts_kernel<<<1, 64, 0, stream>>>(src, starts, ntot);

  // qkv = zn @ [Wq|Wk|Wv]  -> bf16 [ntot][1536]
  gemm_bt<1536, false, false><<<dim3(ntot / 64, 24), 256, 0, stream>>>(zn, WtQKV, nullptr, qkv, nullptr);

  // per-graph attention, one wave per (row, head)
  attn_kernel<<<(ntot * NHEADS) / 4, 256, 0, stream>>>(qkv, starts, src, obuf, ntot);

  // out = o @ Wo + bo -> fp32 d_out
  gemm_bt<512, true, true><<<dim3(ntot / 64, 8), 256, 0, stream>>>(obuf, WtO, bo, nullptr, out);
}

// Round 2
// 536.484 us; speedup vs baseline: 5.1876x; 5.1876x over previous
//
#include <hip/hip_runtime.h>
#include <hip/hip_bf16.h>
#include <math.h>

#define DIN 512
#define DIM 512
#define NHEADS 8
#define DHEAD 64
#define NB 32

typedef __attribute__((ext_vector_type(8))) short bf16x8;
typedef __attribute__((ext_vector_type(8))) unsigned short u16x8;
typedef __attribute__((ext_vector_type(4))) float f32x4;

__device__ inline unsigned short f2bf(float x) {
  unsigned int u = __float_as_uint(x);
  unsigned int r = (u + 0x7FFFu + ((u >> 16) & 1u)) >> 16;
  return (unsigned short)r;
}
__device__ inline float bf2f(unsigned short h) {
  return __uint_as_float(((unsigned int)h) << 16);
}

// ---------------- LayerNorm: one wave (64 lanes) per row of 512 ----------------
__global__ __launch_bounds__(256) void ln_kernel(const float* __restrict__ z,
                                                 const float* __restrict__ gamma,
                                                 const float* __restrict__ beta,
                                                 unsigned short* __restrict__ zn,
                                                 int ntot) {
  int wave = (blockIdx.x * blockDim.x + threadIdx.x) >> 6;
  int lane = threadIdx.x & 63;
  if (wave >= ntot) return;
  const float* row = z + (size_t)wave * DIN;
  float4 a = ((const float4*)row)[lane];
  float4 b = ((const float4*)row)[64 + lane];
  float s  = a.x + a.y + a.z + a.w + b.x + b.y + b.z + b.w;
  float sq = a.x*a.x + a.y*a.y + a.z*a.z + a.w*a.w
           + b.x*b.x + b.y*b.y + b.z*b.z + b.w*b.w;
#pragma unroll
  for (int off = 32; off; off >>= 1) {
    s  += __shfl_xor(s, off);
    sq += __shfl_xor(sq, off);
  }
  float mu  = s * (1.0f / DIN);
  float var = sq * (1.0f / DIN) - mu * mu;
  float r   = rsqrtf(var + 1e-5f);

  float4 g0 = ((const float4*)gamma)[lane];
  float4 g1 = ((const float4*)gamma)[64 + lane];
  float4 b0 = ((const float4*)beta)[lane];
  float4 b1 = ((const float4*)beta)[64 + lane];

  ushort4 o0, o1;
  o0.x = f2bf((a.x - mu) * r * g0.x + b0.x);
  o0.y = f2bf((a.y - mu) * r * g0.y + b0.y);
  o0.z = f2bf((a.z - mu) * r * g0.z + b0.z);
  o0.w = f2bf((a.w - mu) * r * g0.w + b0.w);
  o1.x = f2bf((b.x - mu) * r * g1.x + b1.x);
  o1.y = f2bf((b.y - mu) * r * g1.y + b1.y);
  o1.z = f2bf((b.z - mu) * r * g1.z + b1.z);
  o1.w = f2bf((b.w - mu) * r * g1.w + b1.w);
  ((ushort4*)(zn + (size_t)wave * DIN))[lane] = o0;
  ((ushort4*)(zn + (size_t)wave * DIN))[64 + lane] = o1;
}

// ---------------- graph starts via binary search over sorted src ----------------
__global__ void starts_kernel(const int* __restrict__ src, int* __restrict__ starts, int ntot) {
  int b = threadIdx.x;
  if (b > NB) return;
  int lo = 0, hi = ntot;
  while (lo < hi) {
    int mid = (lo + hi) >> 1;
    if (src[mid] < b) lo = mid + 1; else hi = mid;
  }
  starts[b] = lo;
}

// ---------------- weight transpose + bf16 convert: Wt[n][k] = W[k][n] ----------------
__global__ __launch_bounds__(256) void wtrans_kernel(const float* __restrict__ W,
                                                     unsigned short* __restrict__ Wt) {
  __shared__ float tile[32][33];
  int k0 = blockIdx.x * 32;
  int n0 = blockIdx.y * 32;
  int tx = threadIdx.x & 31;
  int ty = threadIdx.x >> 5;  // 0..7
#pragma unroll
  for (int i = 0; i < 4; i++)
    tile[ty + i * 8][tx] = W[(size_t)(k0 + ty + i * 8) * DIM + n0 + tx];
  __syncthreads();
#pragma unroll
  for (int i = 0; i < 4; i++)
    Wt[(size_t)(n0 + ty + i * 8) * DIN + k0 + tx] = f2bf(tile[tx][ty + i * 8]);
}

// ---------------- V transpose: vtg[c][node] = qkv[node][1024 + c] ----------------
__global__ __launch_bounds__(256) void vtrans_kernel(const unsigned short* __restrict__ qkv,
                                                     unsigned short* __restrict__ vtg,
                                                     int ntot) {
  __shared__ unsigned short tile[64][72];
  int n0 = blockIdx.x * 64;
  int c0 = blockIdx.y * 64;
  int tcol = (threadIdx.x & 7) * 8;
  int trow = threadIdx.x >> 3;  // 0..31
#pragma unroll
  for (int p = 0; p < 2; p++) {
    int node = n0 + trow + p * 32;
    *(u16x8*)&tile[trow + p * 32][tcol] =
        *(const u16x8*)(qkv + (size_t)node * 1536 + 1024 + c0 + tcol);
  }
  __syncthreads();
  int nodeoff = (threadIdx.x & 7) * 8;
#pragma unroll
  for (int p = 0; p < 2; p++) {
    int c = (threadIdx.x >> 3) + p * 32;
    u16x8 v;
#pragma unroll
    for (int i = 0; i < 8; i++) v[i] = tile[nodeoff + i][c];
    *(u16x8*)(vtg + (size_t)(c0 + c) * ntot + n0 + nodeoff) = v;
  }
}

// ---------------- bf16 MFMA GEMM, B^T layout ----------------
template <int N, bool BIAS, bool OUT_F32>
__global__ __launch_bounds__(256) void gemm_bt(const unsigned short* __restrict__ A,
                                               const unsigned short* __restrict__ Bt,
                                               const float* __restrict__ bias,
                                               unsigned short* __restrict__ Cbf,
                                               float* __restrict__ Cf) {
  int lane = threadIdx.x & 63;
  int wv   = threadIdx.x >> 6;
  int m0   = (blockIdx.x * 4 + wv) * 16;
  int n0   = blockIdx.y * 64;
  int quad = lane >> 4;
  int mi   = lane & 15;

  const unsigned short* arow = A  + (size_t)(m0 + mi) * DIN + quad * 8;
  const unsigned short* brow = Bt + (size_t)(n0 + mi) * DIN + quad * 8;

  f32x4 acc0 = {0.f, 0.f, 0.f, 0.f};
  f32x4 acc1 = {0.f, 0.f, 0.f, 0.f};
  f32x4 acc2 = {0.f, 0.f, 0.f, 0.f};
  f32x4 acc3 = {0.f, 0.f, 0.f, 0.f};

#pragma unroll 4
  for (int k = 0; k < DIN; k += 32) {
    bf16x8 af  = *(const bf16x8*)(arow + k);
    bf16x8 bf0 = *(const bf16x8*)(brow + k);
    bf16x8 bf1 = *(const bf16x8*)(brow + 16 * DIN + k);
    bf16x8 bf2 = *(const bf16x8*)(brow + 32 * DIN + k);
    bf16x8 bf3 = *(const bf16x8*)(brow + 48 * DIN + k);
    acc0 = __builtin_amdgcn_mfma_f32_16x16x32_bf16(af, bf0, acc0, 0, 0, 0);
    acc1 = __builtin_amdgcn_mfma_f32_16x16x32_bf16(af, bf1, acc1, 0, 0, 0);
    acc2 = __builtin_amdgcn_mfma_f32_16x16x32_bf16(af, bf2, acc2, 0, 0, 0);
    acc3 = __builtin_amdgcn_mfma_f32_16x16x32_bf16(af, bf3, acc3, 0, 0, 0);
  }

  f32x4 accs[4] = {acc0, acc1, acc2, acc3};
  int r0 = m0 + quad * 4;
#pragma unroll
  for (int j = 0; j < 4; j++) {
    int col = n0 + j * 16 + mi;
    float bv = BIAS ? bias[col] : 0.f;
#pragma unroll
    for (int r = 0; r < 4; r++) {
      float val = accs[j][r] + bv;
      size_t idx = (size_t)(r0 + r) * N + col;
      if (OUT_F32) Cf[idx] = val; else Cbf[idx] = f2bf(val);
    }
  }
}

// ---------------- flash attention over compact graphs ----------------
// block = 4 waves; wave = 16 queries x d=64 for one (graph, head, qtile)
__global__ __launch_bounds__(256) void fattn_kernel(const unsigned short* __restrict__ qkv,
                                                    const unsigned short* __restrict__ vtg,
                                                    const int* __restrict__ starts,
                                                    unsigned short* __restrict__ o,
                                                    int ntot) {
  __shared__ unsigned short p_lds_all[4][16][56];  // stride 56: 16B-aligned rows, <=2-way bank alias
  int g  = blockIdx.x;
  int h  = blockIdx.y;
  int qt = blockIdx.z;
  int st = starts[g];
  int n  = starts[g + 1] - st;
  int wv   = threadIdx.x >> 6;
  int lane = threadIdx.x & 63;
  int q0 = qt * 64 + wv * 16;
  if (q0 >= n) return;
  int col  = lane & 15;
  int quad = lane >> 4;
  unsigned short (*p_lds)[56] = p_lds_all[wv];

  // Q fragments (A-layout), scale folded into S later
  int qrow = q0 + col; if (qrow >= n) qrow = n - 1;
  const unsigned short* qptr = qkv + (size_t)(st + qrow) * 1536 + h * 64 + quad * 8;
  bf16x8 qf0 = *(const bf16x8*)(qptr);
  bf16x8 qf1 = *(const bf16x8*)(qptr + 32);

  const unsigned short* kbase = qkv + 512 + (size_t)h * 64;     // + node*1536
  const unsigned short* vbase = vtg + (size_t)(h * 64) * ntot + st;

  f32x4 oa0 = {0,0,0,0}, oa1 = {0,0,0,0}, oa2 = {0,0,0,0}, oa3 = {0,0,0,0};
  float mr[4] = {-1e30f, -1e30f, -1e30f, -1e30f};
  float lr[4] = {0.f, 0.f, 0.f, 0.f};

  for (int kt = 0; kt < n; kt += 32) {
    // ---- S = Q K^T for keys [kt, kt+32) ----
    int k0r = kt + col, k1r = kt + 16 + col;
    int kk0 = k0r < n ? k0r : n - 1;
    int kk1 = k1r < n ? k1r : n - 1;
    const unsigned short* kp0 = kbase + (size_t)(st + kk0) * 1536 + quad * 8;
    const unsigned short* kp1 = kbase + (size_t)(st + kk1) * 1536 + quad * 8;
    f32x4 s0 = {0,0,0,0}, s1 = {0,0,0,0};
    {
      bf16x8 kf00 = *(const bf16x8*)(kp0);
      bf16x8 kf01 = *(const bf16x8*)(kp0 + 32);
      bf16x8 kf10 = *(const bf16x8*)(kp1);
      bf16x8 kf11 = *(const bf16x8*)(kp1 + 32);
      s0 = __builtin_amdgcn_mfma_f32_16x16x32_bf16(qf0, kf00, s0, 0, 0, 0);
      s0 = __builtin_amdgcn_mfma_f32_16x16x32_bf16(qf1, kf01, s0, 0, 0, 0);
      s1 = __builtin_amdgcn_mfma_f32_16x16x32_bf16(qf0, kf10, s1, 0, 0, 0);
      s1 = __builtin_amdgcn_mfma_f32_16x16x32_bf16(qf1, kf11, s1, 0, 0, 0);
    }
    // scale + mask invalid key columns
    const float sc = 0.125f;  // 1/sqrt(64)
#pragma unroll
    for (int r = 0; r < 4; r++) { s0[r] *= sc; s1[r] *= sc; }
    if (k0r >= n) { s0[0] = -1e30f; s0[1] = -1e30f; s0[2] = -1e30f; s0[3] = -1e30f; }
    if (k1r >= n) { s1[0] = -1e30f; s1[1] = -1e30f; s1[2] = -1e30f; s1[3] = -1e30f; }

    // ---- online softmax (rows live at quad*4+reg; reduce across 16 lanes of quad) ----
    float tmax[4];
#pragma unroll
    for (int r = 0; r < 4; r++) tmax[r] = fmaxf(s0[r], s1[r]);
#pragma unroll
    for (int off = 1; off < 16; off <<= 1) {
#pragma unroll
      for (int r = 0; r < 4; r++) tmax[r] = fmaxf(tmax[r], __shfl_xor(tmax[r], off));
    }
    float c[4], psum[4];
#pragma unroll
    for (int r = 0; r < 4; r++) {
      float mn = fmaxf(mr[r], tmax[r]);
      c[r] = __expf(mr[r] - mn);
      mr[r] = mn;
      float p0 = __expf(s0[r] - mn);
      float p1 = __expf(s1[r] - mn);
      s0[r] = p0; s1[r] = p1;
      psum[r] = p0 + p1;
    }
#pragma unroll
    for (int off = 1; off < 16; off <<= 1) {
#pragma unroll
      for (int r = 0; r < 4; r++) psum[r] += __shfl_xor(psum[r], off);
    }
#pragma unroll
    for (int r = 0; r < 4; r++) {
      lr[r] = lr[r] * c[r] + psum[r];
      oa0[r] *= c[r]; oa1[r] *= c[r]; oa2[r] *= c[r]; oa3[r] *= c[r];
    }

    // ---- P: C-layout -> A-layout via per-wave LDS ----
#pragma unroll
    for (int r = 0; r < 4; r++) {
      p_lds[quad * 4 + r][col]      = f2bf(s0[r]);
      p_lds[quad * 4 + r][16 + col] = f2bf(s1[r]);
    }
    __builtin_amdgcn_fence(__ATOMIC_ACQ_REL, "workgroup");  // lgkm drain; wave-lockstep makes this sufficient
    bf16x8 pf = *(const bf16x8*)(&p_lds[col][quad * 8]);

    // ---- O += P V  (V^T fragments direct from global, contiguous along keys) ----
    const unsigned short* vp = vbase + kt + quad * 8;
    bf16x8 vf0 = *(const bf16x8*)(vp + (size_t)(col) * ntot);
    bf16x8 vf1 = *(const bf16x8*)(vp + (size_t)(16 + col) * ntot);
    bf16x8 vf2 = *(const bf16x8*)(vp + (size_t)(32 + col) * ntot);
    bf16x8 vf3 = *(const bf16x8*)(vp + (size_t)(48 + col) * ntot);
    oa0 = __builtin_amdgcn_mfma_f32_16x16x32_bf16(pf, vf0, oa0, 0, 0, 0);
    oa1 = __builtin_amdgcn_mfma_f32_16x16x32_bf16(pf, vf1, oa1, 0, 0, 0);
    oa2 = __builtin_amdgcn_mfma_f32_16x16x32_bf16(pf, vf2, oa2, 0, 0, 0);
    oa3 = __builtin_amdgcn_mfma_f32_16x16x32_bf16(pf, vf3, oa3, 0, 0, 0);
  }

  // ---- store O (rows quad*4+r, cols dchunk*16+col) ----
#pragma unroll
  for (int r = 0; r < 4; r++) {
    int q = q0 + quad * 4 + r;
    if (q < n) {
      float inv = 1.0f / lr[r];
      unsigned short* orow = o + (size_t)(st + q) * DIM + h * 64 + col;
      orow[0]  = f2bf(oa0[r] * inv);
      orow[16] = f2bf(oa1[r] * inv);
      orow[32] = f2bf(oa2[r] * inv);
      orow[48] = f2bf(oa3[r] * inv);
    }
  }
}

extern "C" void kernel_launch(void* const* d_in, const int* in_sizes, int n_in,
                              void* d_out, int out_size, void* d_ws, size_t ws_size,
                              hipStream_t stream) {
  const float* z     = (const float*)d_in[0];
  const int*   src   = (const int*)d_in[1];
  const float* gamma = (const float*)d_in[2];
  const float* beta  = (const float*)d_in[3];
  const float* Wq    = (const float*)d_in[4];
  const float* Wk    = (const float*)d_in[5];
  const float* Wv    = (const float*)d_in[6];
  const float* Wo    = (const float*)d_in[7];
  const float* bo    = (const float*)d_in[8];
  int ntot = in_sizes[0] / DIN;
  float* out = (float*)d_out;

  char* ws = (char*)d_ws;
  size_t off = 0;
  unsigned short* zn    = (unsigned short*)(ws + off); off += (size_t)ntot * DIN * 2;
  unsigned short* qkv   = (unsigned short*)(ws + off); off += (size_t)ntot * 1536 * 2;
  unsigned short* obuf  = (unsigned short*)(ws + off); off += (size_t)ntot * DIM * 2;
  unsigned short* vtg   = (unsigned short*)(ws + off); off += ((size_t)ntot * DIM + 256) * 2;  // +slack for tail frag reads
  unsigned short* WtQKV = (unsigned short*)(ws + off); off += (size_t)1536 * DIN * 2;
  unsigned short* WtO   = (unsigned short*)(ws + off); off += (size_t)DIM * DIN * 2;
  int* starts           = (int*)(ws + off);

  wtrans_kernel<<<dim3(16, 16), 256, 0, stream>>>(Wq, WtQKV);
  wtrans_kernel<<<dim3(16, 16), 256, 0, stream>>>(Wk, WtQKV + (size_t)512 * DIN);
  wtrans_kernel<<<dim3(16, 16), 256, 0, stream>>>(Wv, WtQKV + (size_t)1024 * DIN);
  wtrans_kernel<<<dim3(16, 16), 256, 0, stream>>>(Wo, WtO);

  ln_kernel<<<ntot / 4, 256, 0, stream>>>(z, gamma, beta, zn, ntot);
  starts_kernel<<<1, 64, 0, stream>>>(src, starts, ntot);

  // qkv = zn @ [Wq|Wk|Wv] -> bf16 [ntot][1536]
  gemm_bt<1536, false, false><<<dim3(ntot / 64, 24), 256, 0, stream>>>(zn, WtQKV, nullptr, qkv, nullptr);

  // v columns transposed: vtg[c][node]
  vtrans_kernel<<<dim3(ntot / 64, 8), 256, 0, stream>>>(qkv, vtg, ntot);

  // flash attention: grid (graphs, heads, qtiles up to 512/64)
  fattn_kernel<<<dim3(NB, NHEADS, 8), 256, 0, stream>>>(qkv, vtg, starts, obuf, ntot);

  // out = o @ Wo + bo -> fp32
  gemm_bt<512, true, true><<<dim3(ntot / 64, 8), 256, 0, stream>>>(obuf, WtO, bo, nullptr, out);
}

// Round 3
// 211.963 us; speedup vs baseline: 13.1300x; 2.5310x over previous
//
#include <hip/hip_runtime.h>
#include <hip/hip_bf16.h>
#include <math.h>

#define DIN 512
#define DIM 512
#define NHEADS 8
#define DHEAD 64
#define NB 32
#define NPAD 512              // per-graph padded node slots
#define NPTOT (NB * NPAD)     // 16384

typedef __attribute__((ext_vector_type(8))) short bf16x8;
typedef __attribute__((ext_vector_type(8))) unsigned short u16x8;
typedef __attribute__((ext_vector_type(4))) float f32x4;

typedef __attribute__((address_space(3))) unsigned int lds_u32;
typedef __attribute__((address_space(1))) const unsigned int g_u32;

__device__ __forceinline__ void gll16(const unsigned short* g, unsigned short* l) {
  __builtin_amdgcn_global_load_lds((g_u32*)g, (lds_u32*)l, 16, 0, 0);
}

__device__ inline unsigned short f2bf(float x) {
  unsigned int u = __float_as_uint(x);
  unsigned int r = (u + 0x7FFFu + ((u >> 16) & 1u)) >> 16;
  return (unsigned short)r;
}

// ---------------- LayerNorm: one wave per row of 512 ----------------
__global__ __launch_bounds__(256) void ln_kernel(const float* __restrict__ z,
                                                 const float* __restrict__ gamma,
                                                 const float* __restrict__ beta,
                                                 unsigned short* __restrict__ zn,
                                                 int ntot) {
  int wave = (blockIdx.x * blockDim.x + threadIdx.x) >> 6;
  int lane = threadIdx.x & 63;
  if (wave >= ntot) return;
  const float* row = z + (size_t)wave * DIN;
  float4 a = ((const float4*)row)[lane];
  float4 b = ((const float4*)row)[64 + lane];
  float s  = a.x + a.y + a.z + a.w + b.x + b.y + b.z + b.w;
  float sq = a.x*a.x + a.y*a.y + a.z*a.z + a.w*a.w
           + b.x*b.x + b.y*b.y + b.z*b.z + b.w*b.w;
#pragma unroll
  for (int off = 32; off; off >>= 1) {
    s  += __shfl_xor(s, off);
    sq += __shfl_xor(sq, off);
  }
  float mu  = s * (1.0f / DIN);
  float var = sq * (1.0f / DIN) - mu * mu;
  float r   = rsqrtf(var + 1e-5f);

  float4 g0 = ((const float4*)gamma)[lane];
  float4 g1 = ((const float4*)gamma)[64 + lane];
  float4 b0 = ((const float4*)beta)[lane];
  float4 b1 = ((const float4*)beta)[64 + lane];

  ushort4 o0, o1;
  o0.x = f2bf((a.x - mu) * r * g0.x + b0.x);
  o0.y = f2bf((a.y - mu) * r * g0.y + b0.y);
  o0.z = f2bf((a.z - mu) * r * g0.z + b0.z);
  o0.w = f2bf((a.w - mu) * r * g0.w + b0.w);
  o1.x = f2bf((b.x - mu) * r * g1.x + b1.x);
  o1.y = f2bf((b.y - mu) * r * g1.y + b1.y);
  o1.z = f2bf((b.z - mu) * r * g1.z + b1.z);
  o1.w = f2bf((b.w - mu) * r * g1.w + b1.w);
  ((ushort4*)(zn + (size_t)wave * DIN))[lane] = o0;
  ((ushort4*)(zn + (size_t)wave * DIN))[64 + lane] = o1;
}

// ---------------- graph starts via binary search over sorted src ----------------
__global__ void starts_kernel(const int* __restrict__ src, int* __restrict__ starts, int ntot) {
  int b = threadIdx.x;
  if (b > NB) return;
  int lo = 0, hi = ntot;
  while (lo < hi) {
    int mid = (lo + hi) >> 1;
    if (src[mid] < b) lo = mid + 1; else hi = mid;
  }
  starts[b] = lo;
}

// ---------------- node -> padded row map ----------------
__global__ __launch_bounds__(256) void mapk(const int* __restrict__ src,
                                            const int* __restrict__ starts,
                                            int* __restrict__ dstrow, int ntot) {
  int i = blockIdx.x * 256 + threadIdx.x;
  if (i < ntot) {
    int g = src[i];
    dstrow[i] = g * NPAD + (i - starts[g]);
  }
}

// ---------------- weight transpose + bf16: Wt[n][k] = W[k][n] ----------------
__global__ __launch_bounds__(256) void wtrans_kernel(const float* __restrict__ W,
                                                     unsigned short* __restrict__ Wt) {
  __shared__ float tile[32][33];
  int k0 = blockIdx.x * 32;
  int n0 = blockIdx.y * 32;
  int tx = threadIdx.x & 31;
  int ty = threadIdx.x >> 5;
#pragma unroll
  for (int i = 0; i < 4; i++)
    tile[ty + i * 8][tx] = W[(size_t)(k0 + ty + i * 8) * DIM + n0 + tx];
  __syncthreads();
#pragma unroll
  for (int i = 0; i < 4; i++)
    Wt[(size_t)(n0 + ty + i * 8) * DIN + k0 + tx] = f2bf(tile[tx][ty + i * 8]);
}

// ---------------- V transpose over padded domain: vtg[c][p] = qkvp[p][1024+c] ----------------
__global__ __launch_bounds__(256) void vtrans_kernel(const unsigned short* __restrict__ qkvp,
                                                     unsigned short* __restrict__ vtg) {
  __shared__ unsigned short tile[64][72];
  int p0 = blockIdx.x * 64;
  int c0 = blockIdx.y * 64;
  int chunk = (threadIdx.x & 7) * 8;
  int r = threadIdx.x >> 3;  // 0..31
#pragma unroll
  for (int p = 0; p < 2; p++) {
    int row = r + p * 32;
    *(u16x8*)&tile[row][chunk] = *(const u16x8*)(qkvp + (size_t)(p0 + row) * 1536 + 1024 + c0 + chunk);
  }
  __syncthreads();
#pragma unroll
  for (int p = 0; p < 2; p++) {
    int c = r + p * 32;
    u16x8 v;
#pragma unroll
    for (int i = 0; i < 8; i++) v[i] = tile[chunk + i][c];
    *(u16x8*)(vtg + (size_t)(c0 + c) * NPTOT + p0 + chunk) = v;
  }
}

// ---------------- m97-style staged GEMM: C[m][n] = sum_k A[m][k] * Bt[n][k], K=512 ----------------
// block 256 thr = 4 waves; tile 128(M) x 128(N) x 32(K); double-buffered global_load_lds;
// XOR swizzle chunk^((row>>1)&3) keeps unpadded b128 frag reads at 2-way alias (free).
template <int NCOLS, bool BIAS, bool OUT_F32, bool REMAP>
__global__ __launch_bounds__(256) void gemm_staged(const unsigned short* __restrict__ A,
                                                   const unsigned short* __restrict__ Bt,
                                                   const float* __restrict__ bias,
                                                   const int* __restrict__ remap,
                                                   unsigned short* __restrict__ Cbf,
                                                   float* __restrict__ Cf) {
  __shared__ unsigned short Al[2][128 * 32];
  __shared__ unsigned short Bl[2][128 * 32];
  int tid = threadIdx.x, lane = tid & 63, wv = tid >> 6;
  int col = lane & 15, quad = lane >> 4;
  int m0 = blockIdx.x * 128, n0 = blockIdx.y * 128;
  int msub = (wv & 1) * 64, nsub = (wv >> 1) * 64;

  int srow = lane >> 2;                                   // 0..15
  int cswz = (((lane & 3) ^ ((lane >> 3) & 3))) * 8;      // swizzled k-chunk (ushorts)

  f32x4 acc[4][4];
#pragma unroll
  for (int i = 0; i < 4; i++)
#pragma unroll
    for (int j = 0; j < 4; j++) acc[i][j] = (f32x4){0.f, 0.f, 0.f, 0.f};

  auto stage = [&](int ks, int nb) {
    const unsigned short* Ab = A  + (size_t)m0 * DIN + ks * 32;
    const unsigned short* Bb = Bt + (size_t)n0 * DIN + ks * 32;
#pragma unroll
    for (int i = 0; i < 2; i++) {
      int t = wv * 2 + i;  // 0..7 -> rows t*16..t*16+16
      gll16(Ab + (size_t)(t * 16 + srow) * DIN + cswz, &Al[nb][t * 512]);
      gll16(Bb + (size_t)(t * 16 + srow) * DIN + cswz, &Bl[nb][t * 512]);
    }
  };

  stage(0, 0);
#pragma unroll 2
  for (int ks = 0; ks < 16; ks++) {
    int cur = ks & 1;
    __syncthreads();  // drains vmcnt -> buf[cur] ready; all waves past prior compute
    if (ks + 1 < 16) stage(ks + 1, 1 - cur);
    bf16x8 af[4], bfr[4];
#pragma unroll
    for (int mt = 0; mt < 4; mt++) {
      int row = msub + mt * 16 + col;
      af[mt] = *(const bf16x8*)&Al[cur][row * 32 + ((quad ^ ((row >> 1) & 3)) * 8)];
    }
#pragma unroll
    for (int nt = 0; nt < 4; nt++) {
      int row = nsub + nt * 16 + col;
      bfr[nt] = *(const bf16x8*)&Bl[cur][row * 32 + ((quad ^ ((row >> 1) & 3)) * 8)];
    }
#pragma unroll
    for (int mt = 0; mt < 4; mt++)
#pragma unroll
      for (int nt = 0; nt < 4; nt++)
        acc[mt][nt] = __builtin_amdgcn_mfma_f32_16x16x32_bf16(af[mt], bfr[nt], acc[mt][nt], 0, 0, 0);
  }

  // epilogue
#pragma unroll
  for (int mt = 0; mt < 4; mt++) {
#pragma unroll
    for (int r = 0; r < 4; r++) {
      int mrow = m0 + msub + mt * 16 + quad * 4 + r;
      int drow = REMAP ? remap[mrow] : mrow;
#pragma unroll
      for (int nt = 0; nt < 4; nt++) {
        int ncol = n0 + nsub + nt * 16 + col;
        float v = acc[mt][nt][r] + (BIAS ? bias[ncol] : 0.f);
        size_t idx = (size_t)drow * NCOLS + ncol;
        if (OUT_F32) Cf[idx] = v; else Cbf[idx] = f2bf(v);
      }
    }
  }
}

// ---------------- flash attention: block = 4 waves x 32 queries, KT=64 keys, LDS dbuf ----------------
__global__ __launch_bounds__(256) void fattn_kernel(const unsigned short* __restrict__ qkvp,
                                                    const unsigned short* __restrict__ vtg,
                                                    const int* __restrict__ starts,
                                                    unsigned short* __restrict__ obuf) {
  __shared__ unsigned short Kbuf[2][64][72];
  __shared__ unsigned short Vbuf[2][64][72];
  __shared__ unsigned short Plds[4][32][72];
  int g = blockIdx.x, h = blockIdx.y, qt = blockIdx.z;
  int st = starts[g];
  int n  = starts[g + 1] - st;
  int q0b = qt * 128;
  if (q0b >= n) return;  // uniform exit
  int tid = threadIdx.x, lane = tid & 63, wv = tid >> 6;
  int col = lane & 15, quad = lane >> 4;
  int q0 = q0b + wv * 32;
  bool active = q0 < n;
  int ntiles = (n + 63) >> 6;

  // Q fragments (A-layout), rows clamped
  bf16x8 qf[2][2];
  if (active) {
#pragma unroll
    for (int a = 0; a < 2; a++) {
      int qr = q0 + a * 16 + col; if (qr >= n) qr = n - 1;
      const unsigned short* qp = qkvp + (size_t)(g * NPAD + qr) * 1536 + h * 64 + quad * 8;
      qf[a][0] = *(const bf16x8*)(qp);
      qf[a][1] = *(const bf16x8*)(qp + 32);
    }
  }

  int srow = tid >> 2;            // 0..63 (key for K, dim for V)
  int schunk = (tid & 3) * 16;    // 0..48
  u16x8 kreg0, kreg1, vreg0, vreg1;
  auto loadregs = [&](int kt) {
    int kk = kt + srow; if (kk >= n) kk = n - 1;
    const unsigned short* kp = qkvp + (size_t)(g * NPAD + kk) * 1536 + 512 + h * 64 + schunk;
    kreg0 = *(const u16x8*)(kp);
    kreg1 = *(const u16x8*)(kp + 8);
    const unsigned short* vp = vtg + (size_t)(h * 64 + srow) * NPTOT + g * NPAD + kt + schunk;
    vreg0 = *(const u16x8*)(vp);
    vreg1 = *(const u16x8*)(vp + 8);
  };
  auto writelds = [&](int b) {
    *(u16x8*)&Kbuf[b][srow][schunk]     = kreg0;
    *(u16x8*)&Kbuf[b][srow][schunk + 8] = kreg1;
    *(u16x8*)&Vbuf[b][srow][schunk]     = vreg0;
    *(u16x8*)&Vbuf[b][srow][schunk + 8] = vreg1;
  };

  f32x4 oa[2][4];
  float mr[2][4], lr[2][4];
#pragma unroll
  for (int a = 0; a < 2; a++)
#pragma unroll
    for (int i = 0; i < 4; i++) {
      oa[a][i] = (f32x4){0.f, 0.f, 0.f, 0.f};
      mr[a][i] = -1e30f; lr[a][i] = 0.f;
    }

  loadregs(0);
  writelds(0);
  __syncthreads();

  for (int t = 0; t < ntiles; t++) {
    int cur = t & 1;
    if (t + 1 < ntiles) loadregs((t + 1) * 64);  // prefetch next tile into regs
    if (active) {
      // ---- S = Q K^T over 64 keys ----
      f32x4 s[2][4];
#pragma unroll
      for (int a = 0; a < 2; a++)
#pragma unroll
        for (int j = 0; j < 4; j++) s[a][j] = (f32x4){0.f, 0.f, 0.f, 0.f};
#pragma unroll
      for (int j = 0; j < 4; j++) {
        bf16x8 kf0 = *(const bf16x8*)&Kbuf[cur][j * 16 + col][quad * 8];
        bf16x8 kf1 = *(const bf16x8*)&Kbuf[cur][j * 16 + col][32 + quad * 8];
        s[0][j] = __builtin_amdgcn_mfma_f32_16x16x32_bf16(qf[0][0], kf0, s[0][j], 0, 0, 0);
        s[0][j] = __builtin_amdgcn_mfma_f32_16x16x32_bf16(qf[0][1], kf1, s[0][j], 0, 0, 0);
        s[1][j] = __builtin_amdgcn_mfma_f32_16x16x32_bf16(qf[1][0], kf0, s[1][j], 0, 0, 0);
        s[1][j] = __builtin_amdgcn_mfma_f32_16x16x32_bf16(qf[1][1], kf1, s[1][j], 0, 0, 0);
      }
      int kt = t * 64;
#pragma unroll
      for (int j = 0; j < 4; j++) {
        bool valid = (kt + j * 16 + col) < n;
#pragma unroll
        for (int a = 0; a < 2; a++)
#pragma unroll
          for (int r = 0; r < 4; r++)
            s[a][j][r] = valid ? s[a][j][r] * 0.125f : -1e30f;
      }
      // ---- online softmax (rows at quad*4+r; reduce across 16 lanes of quad) ----
      float tm[2][4];
#pragma unroll
      for (int a = 0; a < 2; a++)
#pragma unroll
        for (int r = 0; r < 4; r++)
          tm[a][r] = fmaxf(fmaxf(s[a][0][r], s[a][1][r]), fmaxf(s[a][2][r], s[a][3][r]));
#pragma unroll
      for (int off = 1; off < 16; off <<= 1)
#pragma unroll
        for (int a = 0; a < 2; a++)
#pragma unroll
          for (int r = 0; r < 4; r++) tm[a][r] = fmaxf(tm[a][r], __shfl_xor(tm[a][r], off));
      float cc[2][4], ps[2][4];
#pragma unroll
      for (int a = 0; a < 2; a++)
#pragma unroll
        for (int r = 0; r < 4; r++) {
          float mn = fmaxf(mr[a][r], tm[a][r]);
          cc[a][r] = __expf(mr[a][r] - mn);
          mr[a][r] = mn;
          float p0 = __expf(s[a][0][r] - mn); s[a][0][r] = p0;
          float p1 = __expf(s[a][1][r] - mn); s[a][1][r] = p1;
          float p2 = __expf(s[a][2][r] - mn); s[a][2][r] = p2;
          float p3 = __expf(s[a][3][r] - mn); s[a][3][r] = p3;
          ps[a][r] = (p0 + p1) + (p2 + p3);
        }
#pragma unroll
      for (int off = 1; off < 16; off <<= 1)
#pragma unroll
        for (int a = 0; a < 2; a++)
#pragma unroll
          for (int r = 0; r < 4; r++) ps[a][r] += __shfl_xor(ps[a][r], off);
#pragma unroll
      for (int a = 0; a < 2; a++)
#pragma unroll
        for (int r = 0; r < 4; r++) {
          lr[a][r] = lr[a][r] * cc[a][r] + ps[a][r];
          oa[a][0][r] *= cc[a][r]; oa[a][1][r] *= cc[a][r];
          oa[a][2][r] *= cc[a][r]; oa[a][3][r] *= cc[a][r];
        }
      // ---- P: C-layout -> A-layout via per-wave LDS ----
#pragma unroll
      for (int a = 0; a < 2; a++)
#pragma unroll
        for (int j = 0; j < 4; j++)
#pragma unroll
          for (int r = 0; r < 4; r++)
            Plds[wv][a * 16 + quad * 4 + r][j * 16 + col] = f2bf(s[a][j][r]);
      __builtin_amdgcn_fence(__ATOMIC_ACQ_REL, "workgroup");
      bf16x8 pf[2][2];
#pragma unroll
      for (int a = 0; a < 2; a++) {
        pf[a][0] = *(const bf16x8*)&Plds[wv][a * 16 + col][quad * 8];
        pf[a][1] = *(const bf16x8*)&Plds[wv][a * 16 + col][32 + quad * 8];
      }
      // ---- O += P V ----
#pragma unroll
      for (int dt = 0; dt < 4; dt++) {
        bf16x8 vf0 = *(const bf16x8*)&Vbuf[cur][dt * 16 + col][quad * 8];
        bf16x8 vf1 = *(const bf16x8*)&Vbuf[cur][dt * 16 + col][32 + quad * 8];
        oa[0][dt] = __builtin_amdgcn_mfma_f32_16x16x32_bf16(pf[0][0], vf0, oa[0][dt], 0, 0, 0);
        oa[0][dt] = __builtin_amdgcn_mfma_f32_16x16x32_bf16(pf[0][1], vf1, oa[0][dt], 0, 0, 0);
        oa[1][dt] = __builtin_amdgcn_mfma_f32_16x16x32_bf16(pf[1][0], vf0, oa[1][dt], 0, 0, 0);
        oa[1][dt] = __builtin_amdgcn_mfma_f32_16x16x32_bf16(pf[1][1], vf1, oa[1][dt], 0, 0, 0);
      }
    }
    if (t + 1 < ntiles) writelds(1 - cur);
    __syncthreads();
  }

  if (active) {
#pragma unroll
    for (int a = 0; a < 2; a++)
#pragma unroll
      for (int r = 0; r < 4; r++) {
        int q = q0 + a * 16 + quad * 4 + r;
        if (q < n) {
          float inv = 1.0f / lr[a][r];
          unsigned short* op = obuf + (size_t)(st + q) * DIM + h * 64 + col;
          op[0]  = f2bf(oa[a][0][r] * inv);
          op[16] = f2bf(oa[a][1][r] * inv);
          op[32] = f2bf(oa[a][2][r] * inv);
          op[48] = f2bf(oa[a][3][r] * inv);
        }
      }
  }
}

extern "C" void kernel_launch(void* const* d_in, const int* in_sizes, int n_in,
                              void* d_out, int out_size, void* d_ws, size_t ws_size,
                              hipStream_t stream) {
  const float* z     = (const float*)d_in[0];
  const int*   src   = (const int*)d_in[1];
  const float* gamma = (const float*)d_in[2];
  const float* beta  = (const float*)d_in[3];
  const float* Wq    = (const float*)d_in[4];
  const float* Wk    = (const float*)d_in[5];
  const float* Wv    = (const float*)d_in[6];
  const float* Wo    = (const float*)d_in[7];
  const float* bo    = (const float*)d_in[8];
  int ntot = in_sizes[0] / DIN;
  float* out = (float*)d_out;

  char* ws = (char*)d_ws;
  size_t off = 0;
  unsigned short* zn    = (unsigned short*)(ws + off); off += (size_t)ntot * DIN * 2;
  unsigned short* qkvp  = (unsigned short*)(ws + off); off += (size_t)NPTOT * 1536 * 2;
  unsigned short* obuf  = (unsigned short*)(ws + off); off += (size_t)ntot * DIM * 2;
  unsigned short* vtg   = (unsigned short*)(ws + off); off += (size_t)DIM * NPTOT * 2;
  unsigned short* WtQKV = (unsigned short*)(ws + off); off += (size_t)1536 * DIN * 2;
  unsigned short* WtO   = (unsigned short*)(ws + off); off += (size_t)DIM * DIN * 2;
  int* starts           = (int*)(ws + off);            off += 64 * 4;
  int* dstrow           = (int*)(ws + off);

  wtrans_kernel<<<dim3(16, 16), 256, 0, stream>>>(Wq, WtQKV);
  wtrans_kernel<<<dim3(16, 16), 256, 0, stream>>>(Wk, WtQKV + (size_t)512 * DIN);
  wtrans_kernel<<<dim3(16, 16), 256, 0, stream>>>(Wv, WtQKV + (size_t)1024 * DIN);
  wtrans_kernel<<<dim3(16, 16), 256, 0, stream>>>(Wo, WtO);

  ln_kernel<<<ntot / 4, 256, 0, stream>>>(z, gamma, beta, zn, ntot);
  starts_kernel<<<1, 64, 0, stream>>>(src, starts, ntot);
  mapk<<<(ntot + 255) / 256, 256, 0, stream>>>(src, starts, dstrow, ntot);

  // qkvp[g*512+pos][0..1536) = zn @ [Wq|Wk|Wv] (rows scattered to padded slots)
  gemm_staged<1536, false, false, true>
      <<<dim3(ntot / 128, 12), 256, 0, stream>>>(zn, WtQKV, nullptr, dstrow, qkvp, nullptr);

  // vtg[c][g*512+pos] = V^T over padded domain
  vtrans_kernel<<<dim3(NPTOT / 64, 8), 256, 0, stream>>>(qkvp, vtg);

  // flash attention: grid (graphs, heads, 128-query tiles)
  fattn_kernel<<<dim3(NB, NHEADS, 4), 256, 0, stream>>>(qkvp, vtg, starts, obuf);

  // out = obuf @ Wo + bo -> fp32
  gemm_staged<512, true, true, false>
      <<<dim3(ntot / 128, 4), 256, 0, stream>>>(obuf, WtO, bo, nullptr, nullptr, out);
}

// Round 4
// 185.145 us; speedup vs baseline: 15.0319x; 1.1449x over previous
//
#include <hip/hip_runtime.h>
#include <hip/hip_bf16.h>
#include <math.h>

#define DIN 512
#define DIM 512
#define NHEADS 8
#define DHEAD 64
#define NB 32
#define NPAD 512              // per-graph padded node slots
#define NPTOT (NB * NPAD)     // 16384

typedef __attribute__((ext_vector_type(8))) short bf16x8;
typedef __attribute__((ext_vector_type(8))) unsigned short u16x8;
typedef __attribute__((ext_vector_type(4))) float f32x4;

typedef __attribute__((address_space(3))) unsigned int lds_u32;
typedef __attribute__((address_space(1))) const unsigned int g_u32;

__device__ __forceinline__ void gll16(const unsigned short* g, unsigned short* l) {
  __builtin_amdgcn_global_load_lds((g_u32*)g, (lds_u32*)l, 16, 0, 0);
}

__device__ inline unsigned short f2bf(float x) {
  unsigned int u = __float_as_uint(x);
  unsigned int r = (u + 0x7FFFu + ((u >> 16) & 1u)) >> 16;
  return (unsigned short)r;
}

// ---------------- LayerNorm: one wave per row of 512 ----------------
__global__ __launch_bounds__(256) void ln_kernel(const float* __restrict__ z,
                                                 const float* __restrict__ gamma,
                                                 const float* __restrict__ beta,
                                                 unsigned short* __restrict__ zn,
                                                 int ntot) {
  int wave = (blockIdx.x * blockDim.x + threadIdx.x) >> 6;
  int lane = threadIdx.x & 63;
  if (wave >= ntot) return;
  const float* row = z + (size_t)wave * DIN;
  float4 a = ((const float4*)row)[lane];
  float4 b = ((const float4*)row)[64 + lane];
  float s  = a.x + a.y + a.z + a.w + b.x + b.y + b.z + b.w;
  float sq = a.x*a.x + a.y*a.y + a.z*a.z + a.w*a.w
           + b.x*b.x + b.y*b.y + b.z*b.z + b.w*b.w;
#pragma unroll
  for (int off = 32; off; off >>= 1) {
    s  += __shfl_xor(s, off);
    sq += __shfl_xor(sq, off);
  }
  float mu  = s * (1.0f / DIN);
  float var = sq * (1.0f / DIN) - mu * mu;
  float r   = rsqrtf(var + 1e-5f);

  float4 g0 = ((const float4*)gamma)[lane];
  float4 g1 = ((const float4*)gamma)[64 + lane];
  float4 b0 = ((const float4*)beta)[lane];
  float4 b1 = ((const float4*)beta)[64 + lane];

  ushort4 o0, o1;
  o0.x = f2bf((a.x - mu) * r * g0.x + b0.x);
  o0.y = f2bf((a.y - mu) * r * g0.y + b0.y);
  o0.z = f2bf((a.z - mu) * r * g0.z + b0.z);
  o0.w = f2bf((a.w - mu) * r * g0.w + b0.w);
  o1.x = f2bf((b.x - mu) * r * g1.x + b1.x);
  o1.y = f2bf((b.y - mu) * r * g1.y + b1.y);
  o1.z = f2bf((b.z - mu) * r * g1.z + b1.z);
  o1.w = f2bf((b.w - mu) * r * g1.w + b1.w);
  ((ushort4*)(zn + (size_t)wave * DIN))[lane] = o0;
  ((ushort4*)(zn + (size_t)wave * DIN))[64 + lane] = o1;
}

// ---------------- starts (block 0) + node->padded-row map (all), one launch ----------------
__global__ __launch_bounds__(256) void mapk_starts(const int* __restrict__ src,
                                                   int* __restrict__ starts,
                                                   int* __restrict__ dstrow, int ntot) {
  if (blockIdx.x == 0 && threadIdx.x <= NB) {
    int b = threadIdx.x;
    int lo = 0, hi = ntot;
    while (lo < hi) { int mid = (lo + hi) >> 1; if (src[mid] < b) lo = mid + 1; else hi = mid; }
    starts[b] = lo;
  }
  int i = blockIdx.x * 256 + threadIdx.x;
  if (i < ntot) {
    int g = src[i];
    int lo = 0, hi = ntot;
    while (lo < hi) { int mid = (lo + hi) >> 1; if (src[mid] < g) lo = mid + 1; else hi = mid; }
    dstrow[i] = g * NPAD + (i - lo);
  }
}

// ---------------- all 4 weight transposes in one launch ----------------
__global__ __launch_bounds__(256) void wtrans4(const float* __restrict__ Wq,
                                               const float* __restrict__ Wk,
                                               const float* __restrict__ Wv,
                                               const float* __restrict__ Wo,
                                               unsigned short* __restrict__ WtQKV,
                                               unsigned short* __restrict__ WtO) {
  __shared__ float tile[32][33];
  const float* W; unsigned short* Wt;
  int z = blockIdx.z;
  if (z == 0)      { W = Wq; Wt = WtQKV; }
  else if (z == 1) { W = Wk; Wt = WtQKV + (size_t)512 * DIN; }
  else if (z == 2) { W = Wv; Wt = WtQKV + (size_t)1024 * DIN; }
  else             { W = Wo; Wt = WtO; }
  int k0 = blockIdx.x * 32;
  int n0 = blockIdx.y * 32;
  int tx = threadIdx.x & 31;
  int ty = threadIdx.x >> 5;
#pragma unroll
  for (int i = 0; i < 4; i++)
    tile[ty + i * 8][tx] = W[(size_t)(k0 + ty + i * 8) * DIM + n0 + tx];
  __syncthreads();
#pragma unroll
  for (int i = 0; i < 4; i++)
    Wt[(size_t)(n0 + ty + i * 8) * DIN + k0 + tx] = f2bf(tile[tx][ty + i * 8]);
}

// ---------------- V transpose over padded domain (skips fully-pad tiles) ----------------
__global__ __launch_bounds__(256) void vtrans_kernel(const unsigned short* __restrict__ qkvp,
                                                     unsigned short* __restrict__ vtg,
                                                     const int* __restrict__ starts) {
  __shared__ unsigned short tile[64][72];
  int p0 = blockIdx.x * 64;
  int g = p0 >> 9;
  if ((p0 & 511) >= starts[g + 1] - starts[g]) return;  // fully-pad tile: consumers see P=0
  int c0 = blockIdx.y * 64;
  int chunk = (threadIdx.x & 7) * 8;
  int r = threadIdx.x >> 3;  // 0..31
#pragma unroll
  for (int p = 0; p < 2; p++) {
    int row = r + p * 32;
    *(u16x8*)&tile[row][chunk] = *(const u16x8*)(qkvp + (size_t)(p0 + row) * 1536 + 1024 + c0 + chunk);
  }
  __syncthreads();
#pragma unroll
  for (int p = 0; p < 2; p++) {
    int c = r + p * 32;
    u16x8 v;
#pragma unroll
    for (int i = 0; i < 8; i++) v[i] = tile[chunk + i][c];
    *(u16x8*)(vtg + (size_t)(c0 + c) * NPTOT + p0 + chunk) = v;
  }
}

// ---------------- m97-style staged GEMM: C[m][n] = sum_k A[m][k] * Bt[n][k], K=512 ----------------
template <int NCOLS, bool BIAS, bool OUT_F32, bool REMAP>
__global__ __launch_bounds__(256) void gemm_staged(const unsigned short* __restrict__ A,
                                                   const unsigned short* __restrict__ Bt,
                                                   const float* __restrict__ bias,
                                                   const int* __restrict__ remap,
                                                   unsigned short* __restrict__ Cbf,
                                                   float* __restrict__ Cf) {
  __shared__ unsigned short Al[2][128 * 32];
  __shared__ unsigned short Bl[2][128 * 32];
  int tid = threadIdx.x, lane = tid & 63, wv = tid >> 6;
  int col = lane & 15, quad = lane >> 4;
  int m0 = blockIdx.x * 128, n0 = blockIdx.y * 128;
  int msub = (wv & 1) * 64, nsub = (wv >> 1) * 64;

  int srow = lane >> 2;                                   // 0..15
  int cswz = (((lane & 3) ^ ((lane >> 3) & 3))) * 8;      // swizzled k-chunk (ushorts)

  f32x4 acc[4][4];
#pragma unroll
  for (int i = 0; i < 4; i++)
#pragma unroll
    for (int j = 0; j < 4; j++) acc[i][j] = (f32x4){0.f, 0.f, 0.f, 0.f};

  auto stage = [&](int ks, int nb) {
    const unsigned short* Ab = A  + (size_t)m0 * DIN + ks * 32;
    const unsigned short* Bb = Bt + (size_t)n0 * DIN + ks * 32;
#pragma unroll
    for (int i = 0; i < 2; i++) {
      int t = wv * 2 + i;  // 0..7 -> rows t*16..t*16+16
      gll16(Ab + (size_t)(t * 16 + srow) * DIN + cswz, &Al[nb][t * 512]);
      gll16(Bb + (size_t)(t * 16 + srow) * DIN + cswz, &Bl[nb][t * 512]);
    }
  };

  stage(0, 0);
#pragma unroll 2
  for (int ks = 0; ks < 16; ks++) {
    int cur = ks & 1;
    __syncthreads();
    if (ks + 1 < 16) stage(ks + 1, 1 - cur);
    bf16x8 af[4], bfr[4];
#pragma unroll
    for (int mt = 0; mt < 4; mt++) {
      int row = msub + mt * 16 + col;
      af[mt] = *(const bf16x8*)&Al[cur][row * 32 + ((quad ^ ((row >> 1) & 3)) * 8)];
    }
#pragma unroll
    for (int nt = 0; nt < 4; nt++) {
      int row = nsub + nt * 16 + col;
      bfr[nt] = *(const bf16x8*)&Bl[cur][row * 32 + ((quad ^ ((row >> 1) & 3)) * 8)];
    }
#pragma unroll
    for (int mt = 0; mt < 4; mt++)
#pragma unroll
      for (int nt = 0; nt < 4; nt++)
        acc[mt][nt] = __builtin_amdgcn_mfma_f32_16x16x32_bf16(af[mt], bfr[nt], acc[mt][nt], 0, 0, 0);
  }

#pragma unroll
  for (int mt = 0; mt < 4; mt++) {
#pragma unroll
    for (int r = 0; r < 4; r++) {
      int mrow = m0 + msub + mt * 16 + quad * 4 + r;
      int drow = REMAP ? remap[mrow] : mrow;
#pragma unroll
      for (int nt = 0; nt < 4; nt++) {
        int ncol = n0 + nsub + nt * 16 + col;
        float v = acc[mt][nt][r] + (BIAS ? bias[ncol] : 0.f);
        size_t idx = (size_t)drow * NCOLS + ncol;
        if (OUT_F32) Cf[idx] = v; else Cbf[idx] = f2bf(v);
      }
    }
  }
}

// ---------------- flash attention, no-max softmax, l via ones-MFMA ----------------
// block = 4 waves x 32 queries for one (graph, head, 128-query tile); 64-key LDS dbuf tiles.
// All LDS tiles are [rows][64] (128B rows) with XOR chunk swizzle c' = c ^ (row&7):
// every b128 read/write phase covers each 16B residue exactly 2x -> conflict-free (m136).
__global__ __launch_bounds__(256, 3) void fattn_kernel(const unsigned short* __restrict__ qkvp,
                                                       const unsigned short* __restrict__ vtg,
                                                       const int* __restrict__ starts,
                                                       unsigned short* __restrict__ obuf) {
  __shared__ unsigned short Kbuf[2][64 * 64];
  __shared__ unsigned short Vbuf[2][64 * 64];
  __shared__ unsigned short Plds[4][32 * 64];
  int g = blockIdx.x, h = blockIdx.y, qt = blockIdx.z;
  int st = starts[g];
  int n  = starts[g + 1] - st;
  int q0b = qt * 128;
  if (q0b >= n) return;  // uniform exit
  int tid = threadIdx.x, lane = tid & 63, wv = tid >> 6;
  int col = lane & 15, quad = lane >> 4;
  int q0 = q0b + wv * 32;
  bool active = q0 < n;
  int ntiles = (n + 63) >> 6;

  // Q fragments (A-layout), rows clamped; 1/sqrt(64) applied at exp time
  bf16x8 qf[2][2];
  if (active) {
#pragma unroll
    for (int a = 0; a < 2; a++) {
      int qr = q0 + a * 16 + col; if (qr >= n) qr = n - 1;
      const unsigned short* qp = qkvp + (size_t)(g * NPAD + qr) * 1536 + h * 64 + quad * 8;
      qf[a][0] = *(const bf16x8*)(qp);
      qf[a][1] = *(const bf16x8*)(qp + 32);
    }
  }

  // staging: lane -> row srow (key for K, dim for V), chunk pair sc, sc+1
  int srow = tid >> 2;          // 0..63
  int sc   = (tid & 3) * 2;     // 0,2,4,6
  int woff0 = srow * 64 + ((sc ^ (srow & 7)) * 8);
  int woff1 = srow * 64 + (((sc + 1) ^ (srow & 7)) * 8);
  u16x8 kreg0, kreg1, vreg0, vreg1;
  auto loadregs = [&](int kt) {
    // K rows beyond n read pad garbage (finite poison) -> masked to P=0 later
    const unsigned short* kp = qkvp + (size_t)(g * NPAD + kt + srow) * 1536 + 512 + h * 64 + sc * 8;
    kreg0 = *(const u16x8*)(kp);
    kreg1 = *(const u16x8*)(kp + 8);
    const unsigned short* vp = vtg + (size_t)(h * 64 + srow) * NPTOT + g * NPAD + kt + sc * 8;
    vreg0 = *(const u16x8*)(vp);
    vreg1 = *(const u16x8*)(vp + 8);
  };
  auto writelds = [&](int b) {
    *(u16x8*)&Kbuf[b][woff0] = kreg0;
    *(u16x8*)&Kbuf[b][woff1] = kreg1;
    *(u16x8*)&Vbuf[b][woff0] = vreg0;
    *(u16x8*)&Vbuf[b][woff1] = vreg1;
  };

  // all-ones B-fragment (bf16 1.0): D = P * ones^T gives row-sum l in every column
  bf16x8 onesv;
#pragma unroll
  for (int i = 0; i < 8; i++) onesv[i] = (short)0x3F80;

  f32x4 oa[2][4];
  f32x4 lacc[2];
#pragma unroll
  for (int a = 0; a < 2; a++) {
    lacc[a] = (f32x4){0.f, 0.f, 0.f, 0.f};
#pragma unroll
    for (int i = 0; i < 4; i++) oa[a][i] = (f32x4){0.f, 0.f, 0.f, 0.f};
  }

  loadregs(0);
  writelds(0);
  __syncthreads();

  for (int t = 0; t < ntiles; t++) {
    int cur = t & 1;
    if (t + 1 < ntiles) loadregs((t + 1) * 64);  // prefetch next tile into regs
    if (active) {
      // ---- S = Q K^T over 64 keys ----
      f32x4 s[2][4];
#pragma unroll
      for (int a = 0; a < 2; a++)
#pragma unroll
        for (int j = 0; j < 4; j++) s[a][j] = (f32x4){0.f, 0.f, 0.f, 0.f};
#pragma unroll
      for (int j = 0; j < 4; j++) {
        int R = j * 16 + col;
        bf16x8 kf0 = *(const bf16x8*)&Kbuf[cur][R * 64 + ((quad ^ (R & 7)) * 8)];
        bf16x8 kf1 = *(const bf16x8*)&Kbuf[cur][R * 64 + (((4 + quad) ^ (R & 7)) * 8)];
        s[0][j] = __builtin_amdgcn_mfma_f32_16x16x32_bf16(qf[0][0], kf0, s[0][j], 0, 0, 0);
        s[0][j] = __builtin_amdgcn_mfma_f32_16x16x32_bf16(qf[0][1], kf1, s[0][j], 0, 0, 0);
        s[1][j] = __builtin_amdgcn_mfma_f32_16x16x32_bf16(qf[1][0], kf0, s[1][j], 0, 0, 0);
        s[1][j] = __builtin_amdgcn_mfma_f32_16x16x32_bf16(qf[1][1], kf1, s[1][j], 0, 0, 0);
      }
      // ---- P = exp(S/8), masked; no max subtraction (|S/8| <~ 12, fp32 exp safe) ----
      int kt = t * 64;
#pragma unroll
      for (int j = 0; j < 4; j++) {
        bool valid = (kt + j * 16 + col) < n;
#pragma unroll
        for (int a = 0; a < 2; a++)
#pragma unroll
          for (int r = 0; r < 4; r++)
            s[a][j][r] = valid ? __expf(s[a][j][r] * 0.125f) : 0.f;
      }
      // ---- P: C-layout -> A-layout via per-wave LDS (swizzled scalar writes) ----
#pragma unroll
      for (int a = 0; a < 2; a++)
#pragma unroll
        for (int r = 0; r < 4; r++) {
          int R = a * 16 + quad * 4 + r;
#pragma unroll
          for (int j = 0; j < 4; j++) {
            int chunk = j * 2 + (col >> 3);
            Plds[wv][R * 64 + ((chunk ^ (R & 7)) * 8) + (col & 7)] = f2bf(s[a][j][r]);
          }
        }
      __builtin_amdgcn_fence(__ATOMIC_ACQ_REL, "workgroup");
      bf16x8 pf[2][2];
#pragma unroll
      for (int a = 0; a < 2; a++) {
        int R = a * 16 + col;
        pf[a][0] = *(const bf16x8*)&Plds[wv][R * 64 + ((quad ^ (col & 7)) * 8)];
        pf[a][1] = *(const bf16x8*)&Plds[wv][R * 64 + (((4 + quad) ^ (col & 7)) * 8)];
      }
      // ---- O += P V ; l += P * 1 ----
#pragma unroll
      for (int dt = 0; dt < 4; dt++) {
        int R = dt * 16 + col;
        bf16x8 vf0 = *(const bf16x8*)&Vbuf[cur][R * 64 + ((quad ^ (R & 7)) * 8)];
        bf16x8 vf1 = *(const bf16x8*)&Vbuf[cur][R * 64 + (((4 + quad) ^ (R & 7)) * 8)];
        oa[0][dt] = __builtin_amdgcn_mfma_f32_16x16x32_bf16(pf[0][0], vf0, oa[0][dt], 0, 0, 0);
        oa[0][dt] = __builtin_amdgcn_mfma_f32_16x16x32_bf16(pf[0][1], vf1, oa[0][dt], 0, 0, 0);
        oa[1][dt] = __builtin_amdgcn_mfma_f32_16x16x32_bf16(pf[1][0], vf0, oa[1][dt], 0, 0, 0);
        oa[1][dt] = __builtin_amdgcn_mfma_f32_16x16x32_bf16(pf[1][1], vf1, oa[1][dt], 0, 0, 0);
      }
      lacc[0] = __builtin_amdgcn_mfma_f32_16x16x32_bf16(pf[0][0], onesv, lacc[0], 0, 0, 0);
      lacc[0] = __builtin_amdgcn_mfma_f32_16x16x32_bf16(pf[0][1], onesv, lacc[0], 0, 0, 0);
      lacc[1] = __builtin_amdgcn_mfma_f32_16x16x32_bf16(pf[1][0], onesv, lacc[1], 0, 0, 0);
      lacc[1] = __builtin_amdgcn_mfma_f32_16x16x32_bf16(pf[1][1], onesv, lacc[1], 0, 0, 0);
    }
    if (t + 1 < ntiles) writelds(1 - cur);
    __syncthreads();
  }

  if (active) {
#pragma unroll
    for (int a = 0; a < 2; a++)
#pragma unroll
      for (int r = 0; r < 4; r++) {
        int q = q0 + a * 16 + quad * 4 + r;
        if (q < n) {
          float inv = 1.0f / lacc[a][r];
          unsigned short* op = obuf + (size_t)(st + q) * DIM + h * 64 + col;
          op[0]  = f2bf(oa[a][0][r] * inv);
          op[16] = f2bf(oa[a][1][r] * inv);
          op[32] = f2bf(oa[a][2][r] * inv);
          op[48] = f2bf(oa[a][3][r] * inv);
        }
      }
  }
}

extern "C" void kernel_launch(void* const* d_in, const int* in_sizes, int n_in,
                              void* d_out, int out_size, void* d_ws, size_t ws_size,
                              hipStream_t stream) {
  const float* z     = (const float*)d_in[0];
  const int*   src   = (const int*)d_in[1];
  const float* gamma = (const float*)d_in[2];
  const float* beta  = (const float*)d_in[3];
  const float* Wq    = (const float*)d_in[4];
  const float* Wk    = (const float*)d_in[5];
  const float* Wv    = (const float*)d_in[6];
  const float* Wo    = (const float*)d_in[7];
  const float* bo    = (const float*)d_in[8];
  int ntot = in_sizes[0] / DIN;
  float* out = (float*)d_out;

  char* ws = (char*)d_ws;
  size_t off = 0;
  unsigned short* zn    = (unsigned short*)(ws + off); off += (size_t)ntot * DIN * 2;
  unsigned short* qkvp  = (unsigned short*)(ws + off); off += (size_t)NPTOT * 1536 * 2;
  unsigned short* obuf  = (unsigned short*)(ws + off); off += (size_t)ntot * DIM * 2;
  unsigned short* vtg   = (unsigned short*)(ws + off); off += (size_t)DIM * NPTOT * 2;
  unsigned short* WtQKV = (unsigned short*)(ws + off); off += (size_t)1536 * DIN * 2;
  unsigned short* WtO   = (unsigned short*)(ws + off); off += (size_t)DIM * DIN * 2;
  int* starts           = (int*)(ws + off);            off += 64 * 4;
  int* dstrow           = (int*)(ws + off);

  wtrans4<<<dim3(16, 16, 4), 256, 0, stream>>>(Wq, Wk, Wv, Wo, WtQKV, WtO);
  ln_kernel<<<ntot / 4, 256, 0, stream>>>(z, gamma, beta, zn, ntot);
  mapk_starts<<<(ntot + 255) / 256, 256, 0, stream>>>(src, starts, dstrow, ntot);

  // qkvp[g*512+pos][0..1536) = zn @ [Wq|Wk|Wv] (rows scattered to padded slots)
  gemm_staged<1536, false, false, true>
      <<<dim3(ntot / 128, 12), 256, 0, stream>>>(zn, WtQKV, nullptr, dstrow, qkvp, nullptr);

  // vtg[c][g*512+pos] = V^T over padded domain
  vtrans_kernel<<<dim3(NPTOT / 64, 8), 256, 0, stream>>>(qkvp, vtg, starts);

  // flash attention: grid (graphs, heads, 128-query tiles)
  fattn_kernel<<<dim3(NB, NHEADS, 4), 256, 0, stream>>>(qkvp, vtg, starts, obuf);

  // out = obuf @ Wo + bo -> fp32
  gemm_staged<512, true, true, false>
      <<<dim3(ntot / 128, 4), 256, 0, stream>>>(obuf, WtO, bo, nullptr, nullptr, out);
}

// Round 5
// 171.133 us; speedup vs baseline: 16.2627x; 1.0819x over previous
//
#include <hip/hip_runtime.h>
#include <hip/hip_bf16.h>
#include <math.h>

#define DIN 512
#define DIM 512
#define NHEADS 8
#define DHEAD 64
#define NB 32
#define NPAD 512              // per-graph padded node slots
#define NPTOT (NB * NPAD)     // 16384

typedef __attribute__((ext_vector_type(8))) short bf16x8;
typedef __attribute__((ext_vector_type(8))) unsigned short u16x8;
typedef __attribute__((ext_vector_type(4))) float f32x4;

typedef __attribute__((address_space(3))) unsigned int lds_u32;
typedef __attribute__((address_space(1))) const unsigned int g_u32;

__device__ __forceinline__ void gll16(const unsigned short* g, unsigned short* l) {
  __builtin_amdgcn_global_load_lds((g_u32*)g, (lds_u32*)l, 16, 0, 0);
}

__device__ inline unsigned short f2bf(float x) {
  unsigned int u = __float_as_uint(x);
  unsigned int r = (u + 0x7FFFu + ((u >> 16) & 1u)) >> 16;
  return (unsigned short)r;
}

// ---------------- fused prep: LN rows | starts+map | 4 weight transposes ----------------
// grid.x = ntot/4 (LN) + ceil(ntot/256) (map) + 1024 (wtrans 16x16x4)
__global__ __launch_bounds__(256) void prep_kernel(const float* __restrict__ z,
                                                   const float* __restrict__ gamma,
                                                   const float* __restrict__ beta,
                                                   const int* __restrict__ src,
                                                   const float* __restrict__ Wq,
                                                   const float* __restrict__ Wk,
                                                   const float* __restrict__ Wv,
                                                   const float* __restrict__ Wo,
                                                   unsigned short* __restrict__ zn,
                                                   int* __restrict__ starts,
                                                   int* __restrict__ dstrow,
                                                   unsigned short* __restrict__ WtQKV,
                                                   unsigned short* __restrict__ WtO,
                                                   int ntot) {
  __shared__ float tile[32][33];
  int b = blockIdx.x;
  int nln = ntot >> 2;
  int nmap = (ntot + 255) >> 8;
  if (b < nln) {
    // ---- LayerNorm: one wave per row ----
    int wave = b * 4 + (threadIdx.x >> 6);
    int lane = threadIdx.x & 63;
    const float* row = z + (size_t)wave * DIN;
    float4 a = ((const float4*)row)[lane];
    float4 bb = ((const float4*)row)[64 + lane];
    float s  = a.x + a.y + a.z + a.w + bb.x + bb.y + bb.z + bb.w;
    float sq = a.x*a.x + a.y*a.y + a.z*a.z + a.w*a.w
             + bb.x*bb.x + bb.y*bb.y + bb.z*bb.z + bb.w*bb.w;
#pragma unroll
    for (int off = 32; off; off >>= 1) {
      s  += __shfl_xor(s, off);
      sq += __shfl_xor(sq, off);
    }
    float mu  = s * (1.0f / DIN);
    float var = sq * (1.0f / DIN) - mu * mu;
    float r   = rsqrtf(var + 1e-5f);
    float4 g0 = ((const float4*)gamma)[lane];
    float4 g1 = ((const float4*)gamma)[64 + lane];
    float4 b0 = ((const float4*)beta)[lane];
    float4 b1 = ((const float4*)beta)[64 + lane];
    ushort4 o0, o1;
    o0.x = f2bf((a.x - mu) * r * g0.x + b0.x);
    o0.y = f2bf((a.y - mu) * r * g0.y + b0.y);
    o0.z = f2bf((a.z - mu) * r * g0.z + b0.z);
    o0.w = f2bf((a.w - mu) * r * g0.w + b0.w);
    o1.x = f2bf((bb.x - mu) * r * g1.x + b1.x);
    o1.y = f2bf((bb.y - mu) * r * g1.y + b1.y);
    o1.z = f2bf((bb.z - mu) * r * g1.z + b1.z);
    o1.w = f2bf((bb.w - mu) * r * g1.w + b1.w);
    ((ushort4*)(zn + (size_t)wave * DIN))[lane] = o0;
    ((ushort4*)(zn + (size_t)wave * DIN))[64 + lane] = o1;
  } else if (b < nln + nmap) {
    // ---- starts (first block) + node -> padded-slot map ----
    int bid = b - nln;
    if (bid == 0 && threadIdx.x <= NB) {
      int gg = threadIdx.x;
      int lo = 0, hi = ntot;
      while (lo < hi) { int mid = (lo + hi) >> 1; if (src[mid] < gg) lo = mid + 1; else hi = mid; }
      starts[gg] = lo;
    }
    int i = bid * 256 + threadIdx.x;
    if (i < ntot) {
      int gg = src[i];
      int lo = 0, hi = ntot;
      while (lo < hi) { int mid = (lo + hi) >> 1; if (src[mid] < gg) lo = mid + 1; else hi = mid; }
      dstrow[i] = gg * NPAD + (i - lo);
    }
  } else {
    // ---- weight transpose + bf16 convert ----
    int idx = b - nln - nmap;              // 0..1023
    int zz = idx >> 8;                     // which weight
    int rem = idx & 255;
    const float* W; unsigned short* Wt;
    if (zz == 0)      { W = Wq; Wt = WtQKV; }
    else if (zz == 1) { W = Wk; Wt = WtQKV + (size_t)512 * DIN; }
    else if (zz == 2) { W = Wv; Wt = WtQKV + (size_t)1024 * DIN; }
    else              { W = Wo; Wt = WtO; }
    int k0 = (rem & 15) * 32;
    int n0 = (rem >> 4) * 32;
    int tx = threadIdx.x & 31;
    int ty = threadIdx.x >> 5;
#pragma unroll
    for (int i = 0; i < 4; i++)
      tile[ty + i * 8][tx] = W[(size_t)(k0 + ty + i * 8) * DIM + n0 + tx];
    __syncthreads();
#pragma unroll
    for (int i = 0; i < 4; i++)
      Wt[(size_t)(n0 + ty + i * 8) * DIN + k0 + tx] = f2bf(tile[tx][ty + i * 8]);
  }
}

// ---------------- m97-style staged GEMM: C[m][n] = sum_k A[m][k] * Bt[n][k], K=512 ----------------
// 128x128x32 tiles, dbuf global_load_lds; bf16 path: LDS-transposed epilogue -> coalesced 16B stores.
template <int NCOLS, bool BIAS, bool OUT_F32, bool REMAP>
__global__ __launch_bounds__(256) void gemm_staged(const unsigned short* __restrict__ A,
                                                   const unsigned short* __restrict__ Bt,
                                                   const float* __restrict__ bias,
                                                   const int* __restrict__ remap,
                                                   unsigned short* __restrict__ Cbf,
                                                   float* __restrict__ Cf) {
  __shared__ unsigned short smem[16384];   // loop: A dbuf [0,8192) + B dbuf [8192,16384); epilogue: C tile
  int tid = threadIdx.x, lane = tid & 63, wv = tid >> 6;
  int col = lane & 15, quad = lane >> 4;
  int m0 = blockIdx.x * 128, n0 = blockIdx.y * 128;
  int msub = (wv & 1) * 64, nsub = (wv >> 1) * 64;

  int srow = lane >> 2;                                   // 0..15
  int cswz = (((lane & 3) ^ ((lane >> 3) & 3))) * 8;      // swizzled k-chunk (ushorts)

  f32x4 acc[4][4];
#pragma unroll
  for (int i = 0; i < 4; i++)
#pragma unroll
    for (int j = 0; j < 4; j++) acc[i][j] = (f32x4){0.f, 0.f, 0.f, 0.f};

  auto stage = [&](int ks, int nb) {
    const unsigned short* Ab = A  + (size_t)m0 * DIN + ks * 32;
    const unsigned short* Bb = Bt + (size_t)n0 * DIN + ks * 32;
#pragma unroll
    for (int i = 0; i < 2; i++) {
      int t = wv * 2 + i;  // 0..7 -> rows t*16..t*16+16
      gll16(Ab + (size_t)(t * 16 + srow) * DIN + cswz, smem + nb * 4096 + t * 512);
      gll16(Bb + (size_t)(t * 16 + srow) * DIN + cswz, smem + 8192 + nb * 4096 + t * 512);
    }
  };

  stage(0, 0);
#pragma unroll 2
  for (int ks = 0; ks < 16; ks++) {
    int cur = ks & 1;
    __syncthreads();
    if (ks + 1 < 16) stage(ks + 1, 1 - cur);
    bf16x8 af[4], bfr[4];
#pragma unroll
    for (int mt = 0; mt < 4; mt++) {
      int row = msub + mt * 16 + col;
      af[mt] = *(const bf16x8*)&smem[cur * 4096 + row * 32 + ((quad ^ ((row >> 1) & 3)) * 8)];
    }
#pragma unroll
    for (int nt = 0; nt < 4; nt++) {
      int row = nsub + nt * 16 + col;
      bfr[nt] = *(const bf16x8*)&smem[8192 + cur * 4096 + row * 32 + ((quad ^ ((row >> 1) & 3)) * 8)];
    }
#pragma unroll
    for (int mt = 0; mt < 4; mt++)
#pragma unroll
      for (int nt = 0; nt < 4; nt++)
        acc[mt][nt] = __builtin_amdgcn_mfma_f32_16x16x32_bf16(af[mt], bfr[nt], acc[mt][nt], 0, 0, 0);
  }

  if (!OUT_F32) {
    // ---- LDS-transposed epilogue: scalar swizzled LDS writes (2-way banks), coalesced 16B stores ----
    __syncthreads();
#pragma unroll
    for (int mt = 0; mt < 4; mt++)
#pragma unroll
      for (int r = 0; r < 4; r++) {
        int row = msub + mt * 16 + quad * 4 + r;   // (row>>2)&3 == quad
#pragma unroll
        for (int nt = 0; nt < 4; nt++) {
          int c = nsub + nt * 16 + col;
          float v = acc[mt][nt][r] + (BIAS ? bias[n0 + c] : 0.f);
          smem[row * 128 + (((c >> 3) ^ (quad << 1)) * 8) + (c & 7)] = f2bf(v);
        }
      }
    __syncthreads();
#pragma unroll
    for (int pass = 0; pass < 8; pass++) {
      int row = pass * 16 + (tid >> 4);
      int sw  = ((row >> 2) & 3) << 1;
      int ch  = tid & 15;
      u16x8 vv = *(const u16x8*)&smem[row * 128 + ((ch ^ sw) * 8)];
      int drow = REMAP ? remap[m0 + row] : (m0 + row);
      *(u16x8*)(Cbf + (size_t)drow * NCOLS + n0 + ch * 8) = vv;
    }
  } else {
#pragma unroll
    for (int mt = 0; mt < 4; mt++) {
#pragma unroll
      for (int r = 0; r < 4; r++) {
        int mrow = m0 + msub + mt * 16 + quad * 4 + r;
#pragma unroll
        for (int nt = 0; nt < 4; nt++) {
          int ncol = n0 + nsub + nt * 16 + col;
          Cf[(size_t)mrow * NCOLS + ncol] = acc[mt][nt][r] + (BIAS ? bias[ncol] : 0.f);
        }
      }
    }
  }
}

// ---------------- flash attention, no-max softmax, l via ones-MFMA ----------------
// block = 4 waves x 32 queries per (graph, head, 128-query tile); 64-key LDS dbuf tiles.
// K: b128 writes, key-row XOR swizzle. V: transposed in staging (scalar writes, swizzle
// chunk=(srow>>3)^((c>>4)<<1)^(c&7) -> 2 lanes/bank = free). No global V-transpose needed.
__global__ __launch_bounds__(256, 3) void fattn_kernel(const unsigned short* __restrict__ qkvp,
                                                       const int* __restrict__ starts,
                                                       unsigned short* __restrict__ obuf) {
  __shared__ unsigned short Kbuf[2][64 * 64];
  __shared__ unsigned short Vbuf[2][64 * 64];   // [dim][key], swizzled
  __shared__ unsigned short Plds[4][32 * 64];
  int g = blockIdx.x, h = blockIdx.y, qt = blockIdx.z;
  int st = starts[g];
  int n  = starts[g + 1] - st;
  int q0b = qt * 128;
  if (q0b >= n) return;  // uniform exit
  int tid = threadIdx.x, lane = tid & 63, wv = tid >> 6;
  int col = lane & 15, quad = lane >> 4;
  int q0 = q0b + wv * 32;
  bool active = q0 < n;
  int ntiles = (n + 63) >> 6;

  // Q fragments (A-layout); rows q0+a*16+col <= 511 always (pad reads are finite poison, discarded)
  bf16x8 qf[2][2];
  if (active) {
#pragma unroll
    for (int a = 0; a < 2; a++) {
      const unsigned short* qp = qkvp + (size_t)(g * NPAD + q0 + a * 16 + col) * 1536 + h * 64 + quad * 8;
      qf[a][0] = *(const bf16x8*)(qp);
      qf[a][1] = *(const bf16x8*)(qp + 32);
    }
  }

  // staging: thread -> K row srow, k-chunks sc,sc+1; V same row, dims c in [sc*8, sc*8+16)
  int srow = tid >> 2;          // 0..63
  int sc   = (tid & 3) * 2;     // 0,2,4,6
  int woff0 = srow * 64 + ((sc ^ (srow & 7)) * 8);
  int woff1 = srow * 64 + (((sc + 1) ^ (srow & 7)) * 8);
  u16x8 kreg0, kreg1, vreg0, vreg1;
  auto loadregs = [&](int kt) {
    const unsigned short* kp = qkvp + (size_t)(g * NPAD + kt + srow) * 1536 + 512 + h * 64 + sc * 8;
    kreg0 = *(const u16x8*)(kp);
    kreg1 = *(const u16x8*)(kp + 8);
    vreg0 = *(const u16x8*)(kp + 512);    // V lives +512 ushorts after K in the row
    vreg1 = *(const u16x8*)(kp + 520);
  };
  auto writelds = [&](int bsel) {
    *(u16x8*)&Kbuf[bsel][woff0] = kreg0;
    *(u16x8*)&Kbuf[bsel][woff1] = kreg1;
#pragma unroll
    for (int i = 0; i < 8; i++) {
      int c0 = sc * 8 + i;
      int c1 = sc * 8 + 8 + i;
      Vbuf[bsel][c0 * 64 + (((srow >> 3) ^ ((c0 >> 4) << 1) ^ (c0 & 7)) * 8) + (srow & 7)] = vreg0[i];
      Vbuf[bsel][c1 * 64 + (((srow >> 3) ^ ((c1 >> 4) << 1) ^ (c1 & 7)) * 8) + (srow & 7)] = vreg1[i];
    }
  };

  // all-ones B-fragment (bf16 1.0): D = P * ones^T gives row-sum l in every column
  bf16x8 onesv;
#pragma unroll
  for (int i = 0; i < 8; i++) onesv[i] = (short)0x3F80;

  f32x4 oa[2][4];
  f32x4 lacc[2];
#pragma unroll
  for (int a = 0; a < 2; a++) {
    lacc[a] = (f32x4){0.f, 0.f, 0.f, 0.f};
#pragma unroll
    for (int i = 0; i < 4; i++) oa[a][i] = (f32x4){0.f, 0.f, 0.f, 0.f};
  }

  loadregs(0);
  writelds(0);
  __syncthreads();

  for (int t = 0; t < ntiles; t++) {
    int cur = t & 1;
    if (t + 1 < ntiles) loadregs((t + 1) * 64);  // prefetch next tile into regs
    if (active) {
      // ---- S = Q K^T over 64 keys ----
      f32x4 s[2][4];
#pragma unroll
      for (int a = 0; a < 2; a++)
#pragma unroll
        for (int j = 0; j < 4; j++) s[a][j] = (f32x4){0.f, 0.f, 0.f, 0.f};
#pragma unroll
      for (int j = 0; j < 4; j++) {
        int R = j * 16 + col;
        bf16x8 kf0 = *(const bf16x8*)&Kbuf[cur][R * 64 + ((quad ^ (R & 7)) * 8)];
        bf16x8 kf1 = *(const bf16x8*)&Kbuf[cur][R * 64 + (((4 + quad) ^ (R & 7)) * 8)];
        s[0][j] = __builtin_amdgcn_mfma_f32_16x16x32_bf16(qf[0][0], kf0, s[0][j], 0, 0, 0);
        s[0][j] = __builtin_amdgcn_mfma_f32_16x16x32_bf16(qf[0][1], kf1, s[0][j], 0, 0, 0);
        s[1][j] = __builtin_amdgcn_mfma_f32_16x16x32_bf16(qf[1][0], kf0, s[1][j], 0, 0, 0);
        s[1][j] = __builtin_amdgcn_mfma_f32_16x16x32_bf16(qf[1][1], kf1, s[1][j], 0, 0, 0);
      }
      // ---- P = exp(S/8), masked; no max subtraction (|S/8| small, fp32 exp safe) ----
      int kt = t * 64;
#pragma unroll
      for (int j = 0; j < 4; j++) {
        bool valid = (kt + j * 16 + col) < n;
#pragma unroll
        for (int a = 0; a < 2; a++)
#pragma unroll
          for (int r = 0; r < 4; r++)
            s[a][j][r] = valid ? __expf(s[a][j][r] * 0.125f) : 0.f;
      }
      // ---- P: C-layout -> A-layout via per-wave LDS (swizzled scalar writes) ----
#pragma unroll
      for (int a = 0; a < 2; a++)
#pragma unroll
        for (int r = 0; r < 4; r++) {
          int R = a * 16 + quad * 4 + r;
#pragma unroll
          for (int j = 0; j < 4; j++) {
            int chunk = j * 2 + (col >> 3);
            Plds[wv][R * 64 + ((chunk ^ (R & 7)) * 8) + (col & 7)] = f2bf(s[a][j][r]);
          }
        }
      __builtin_amdgcn_fence(__ATOMIC_ACQ_REL, "workgroup");
      bf16x8 pf[2][2];
#pragma unroll
      for (int a = 0; a < 2; a++) {
        int R = a * 16 + col;
        pf[a][0] = *(const bf16x8*)&Plds[wv][R * 64 + ((quad ^ (col & 7)) * 8)];
        pf[a][1] = *(const bf16x8*)&Plds[wv][R * 64 + (((4 + quad) ^ (col & 7)) * 8)];
      }
      // ---- O += P V ; l += P * 1 ----
#pragma unroll
      for (int dt = 0; dt < 4; dt++) {
        int R = dt * 16 + col;
        int gR = ((R >> 4) << 1) ^ (R & 7);
        bf16x8 vf0 = *(const bf16x8*)&Vbuf[cur][R * 64 + ((quad ^ gR) * 8)];
        bf16x8 vf1 = *(const bf16x8*)&Vbuf[cur][R * 64 + (((quad + 4) ^ gR) * 8)];
        oa[0][dt] = __builtin_amdgcn_mfma_f32_16x16x32_bf16(pf[0][0], vf0, oa[0][dt], 0, 0, 0);
        oa[0][dt] = __builtin_amdgcn_mfma_f32_16x16x32_bf16(pf[0][1], vf1, oa[0][dt], 0, 0, 0);
        oa[1][dt] = __builtin_amdgcn_mfma_f32_16x16x32_bf16(pf[1][0], vf0, oa[1][dt], 0, 0, 0);
        oa[1][dt] = __builtin_amdgcn_mfma_f32_16x16x32_bf16(pf[1][1], vf1, oa[1][dt], 0, 0, 0);
      }
      lacc[0] = __builtin_amdgcn_mfma_f32_16x16x32_bf16(pf[0][0], onesv, lacc[0], 0, 0, 0);
      lacc[0] = __builtin_amdgcn_mfma_f32_16x16x32_bf16(pf[0][1], onesv, lacc[0], 0, 0, 0);
      lacc[1] = __builtin_amdgcn_mfma_f32_16x16x32_bf16(pf[1][0], onesv, lacc[1], 0, 0, 0);
      lacc[1] = __builtin_amdgcn_mfma_f32_16x16x32_bf16(pf[1][1], onesv, lacc[1], 0, 0, 0);
    }
    if (t + 1 < ntiles) writelds(1 - cur);
    __syncthreads();
  }

  if (active) {
#pragma unroll
    for (int a = 0; a < 2; a++)
#pragma unroll
      for (int r = 0; r < 4; r++) {
        int q = q0 + a * 16 + quad * 4 + r;
        if (q < n) {
          float inv = 1.0f / lacc[a][r];
          unsigned short* op = obuf + (size_t)(st + q) * DIM + h * 64 + col;
          op[0]  = f2bf(oa[a][0][r] * inv);
          op[16] = f2bf(oa[a][1][r] * inv);
          op[32] = f2bf(oa[a][2][r] * inv);
          op[48] = f2bf(oa[a][3][r] * inv);
        }
      }
  }
}

extern "C" void kernel_launch(void* const* d_in, const int* in_sizes, int n_in,
                              void* d_out, int out_size, void* d_ws, size_t ws_size,
                              hipStream_t stream) {
  const float* z     = (const float*)d_in[0];
  const int*   src   = (const int*)d_in[1];
  const float* gamma = (const float*)d_in[2];
  const float* beta  = (const float*)d_in[3];
  const float* Wq    = (const float*)d_in[4];
  const float* Wk    = (const float*)d_in[5];
  const float* Wv    = (const float*)d_in[6];
  const float* Wo    = (const float*)d_in[7];
  const float* bo    = (const float*)d_in[8];
  int ntot = in_sizes[0] / DIN;
  float* out = (float*)d_out;

  char* ws = (char*)d_ws;
  size_t off = 0;
  unsigned short* zn    = (unsigned short*)(ws + off); off += (size_t)ntot * DIN * 2;
  unsigned short* qkvp  = (unsigned short*)(ws + off); off += (size_t)NPTOT * 1536 * 2;
  unsigned short* obuf  = (unsigned short*)(ws + off); off += (size_t)ntot * DIM * 2;
  unsigned short* WtQKV = (unsigned short*)(ws + off); off += (size_t)1536 * DIN * 2;
  unsigned short* WtO   = (unsigned short*)(ws + off); off += (size_t)DIM * DIN * 2;
  int* starts           = (int*)(ws + off);            off += 64 * 4;
  int* dstrow           = (int*)(ws + off);

  int nln = ntot >> 2;
  int nmap = (ntot + 255) >> 8;
  prep_kernel<<<nln + nmap + 1024, 256, 0, stream>>>(z, gamma, beta, src, Wq, Wk, Wv, Wo,
                                                     zn, starts, dstrow, WtQKV, WtO, ntot);

  // qkvp[g*512+pos][0..1536) = zn @ [Wq|Wk|Wv] (rows scattered to padded slots)
  gemm_staged<1536, false, false, true>
      <<<dim3(ntot / 128, 12), 256, 0, stream>>>(zn, WtQKV, nullptr, dstrow, qkvp, nullptr);

  // flash attention: grid (graphs, heads, 128-query tiles); V transposed in-LDS
  fattn_kernel<<<dim3(NB, NHEADS, 4), 256, 0, stream>>>(qkvp, starts, obuf);

  // out = obuf @ Wo + bo -> fp32
  gemm_staged<512, true, true, false>
      <<<dim3(ntot / 128, 4), 256, 0, stream>>>(obuf, WtO, bo, nullptr, nullptr, out);
}